// Round 4
// baseline (1367.161 us; speedup 1.0000x reference)
//
#include <hip/hip_runtime.h>
#include <stdint.h>

typedef unsigned short u16;
typedef __bf16 bf16_t;
typedef bf16_t bf16x8 __attribute__((ext_vector_type(8)));
typedef float f32x4 __attribute__((ext_vector_type(4)));
typedef u16 u16x4 __attribute__((ext_vector_type(4)));
typedef u16 u16x8 __attribute__((ext_vector_type(8)));

#define HIDDEN 4096
#define NTOK 2048
#define NQ 32
#define NKV 8
#define HD 128
#define QKV_N 6144

#define AS1 __attribute__((address_space(1)))
#define AS3 __attribute__((address_space(3)))

__device__ __forceinline__ u16 f2bf(float f) {
  union { float f; uint32_t u; } v; v.f = f;
  uint32_t u = v.u;
  return (u16)((u + 0x7fffu + ((u >> 16) & 1u)) >> 16);
}

// ---------------- fused prep: hidden cvt + 4 weight transposes ----------------
// blocks 0..8191: hidden fp32->bf16 (float4 per thread)
// blocks 8192+: 64x64 transpose tiles for Wq(4096), Wk(1024), Wv(1024), Wo(4096)
__global__ __launch_bounds__(256) void prep(
    const float* __restrict__ hidden, u16* __restrict__ hid_bf,
    const float* __restrict__ Wq, const float* __restrict__ Wk,
    const float* __restrict__ Wv, const float* __restrict__ Wo,
    u16* __restrict__ WqkvT, u16* __restrict__ WoT) {
  __shared__ float tile[64][65];
  int b = blockIdx.x;
  int t = threadIdx.x;
  if (b < 8192) {
    int i = b * 256 + t;
    float4 v = ((const float4*)hidden)[i];
    u16x4 o; o[0]=f2bf(v.x); o[1]=f2bf(v.y); o[2]=f2bf(v.z); o[3]=f2bf(v.w);
    ((u16x4*)hid_bf)[i] = o;
    return;
  }
  b -= 8192;
  const float* src; u16* dst; int C;
  if (b < 4096)      { src = Wq; dst = WqkvT;                     C = 4096; }
  else if (b < 5120) { src = Wk; dst = WqkvT + (size_t)4096*4096; C = 1024; b -= 4096; }
  else if (b < 6144) { src = Wv; dst = WqkvT + (size_t)5120*4096; C = 1024; b -= 5120; }
  else               { src = Wo; dst = WoT;                       C = 4096; b -= 6144; }
  const int R = 4096;
  int ntx = C >> 6;
  int r0 = (b / ntx) * 64, c0 = (b % ntx) * 64;
  int lr = t >> 4, lc = (t & 15) * 4;
  for (int i = 0; i < 4; i++) {
    float4 v = *(const float4*)&src[(size_t)(r0 + lr + i * 16) * C + c0 + lc];
    tile[lr + i * 16][lc + 0] = v.x;
    tile[lr + i * 16][lc + 1] = v.y;
    tile[lr + i * 16][lc + 2] = v.z;
    tile[lr + i * 16][lc + 3] = v.w;
  }
  __syncthreads();
  int oc = t >> 3, orr = (t & 7) * 8;
  for (int i = 0; i < 2; i++) {
    int c = oc + i * 32;
    u16x8 o;
    for (int e = 0; e < 8; e++) o[e] = f2bf(tile[orr + e][c]);
    *(u16x8*)&dst[(size_t)(c0 + c) * R + r0 + orr] = o;
  }
}

// ---------------- QKV GEMM with fused RMSNorm+RoPE / V-transpose epilogue ----------------
// grid (48, 16): blockIdx.x = head-column (0..31 Q, 32..39 K, 40..47 V), 128 tokens per blockIdx.y.
// Wave cols remapped to wx*16+ni*32+l16 so RoPE partner (d, d+64) = (ni, ni+2) in-lane.
__global__ __launch_bounds__(256, 3) void gemm_qkv(
    const u16* __restrict__ A, const u16* __restrict__ B,
    const int* __restrict__ pos,
    const float* __restrict__ qw, const float* __restrict__ kw,
    u16* __restrict__ Qn, u16* __restrict__ Kn, u16* __restrict__ Vt) {
  const int K = 4096;
  __shared__ u16 sA[128 * 64];
  __shared__ u16 sB[128 * 64];
  __shared__ float S[2][2][4][16];
  const int tid = threadIdx.x;
  const int wave = tid >> 6, lane = tid & 63;
  const int quad = lane >> 4, l16 = lane & 15;
  const int wy = wave >> 1, wx = wave & 1;
  const int h = blockIdx.x;
  const int row0 = blockIdx.y * 128;
  f32x4 acc[4][4] = {};
  const int lr = lane >> 3;
  const int sc = (lane & 7) ^ lr;
  const u16* gA = A + (size_t)(row0 + wave * 32 + lr) * K + sc * 8;
  const u16* gB = B + (size_t)(h * 128 + wave * 32 + lr) * K + sc * 8;
  u16* lA = sA + wave * 32 * 64;
  u16* lB = sB + wave * 32 * 64;
  const int swz = l16 & 7;
  for (int k0 = 0; k0 < K; k0 += 64) {
    for (int j = 0; j < 4; j++) {
      __builtin_amdgcn_global_load_lds(
          (AS1 void*)(void*)(gA + k0 + (size_t)(j * 8) * K),
          (AS3 void*)(void*)(lA + j * 8 * 64), 16, 0, 0);
      __builtin_amdgcn_global_load_lds(
          (AS1 void*)(void*)(gB + k0 + (size_t)(j * 8) * K),
          (AS3 void*)(void*)(lB + j * 8 * 64), 16, 0, 0);
    }
    __syncthreads();
    bf16x8 af[2][4], bfr[2][4];
    for (int s = 0; s < 2; s++) {
      const int c = ((s * 4 + quad) ^ swz) * 8;
      for (int mi = 0; mi < 4; mi++)
        af[s][mi] = *(const bf16x8*)(const void*)(sA + (wy * 64 + mi * 16 + l16) * 64 + c);
      for (int ni = 0; ni < 4; ni++)
        bfr[s][ni] = *(const bf16x8*)(const void*)(sB + (wx * 16 + ni * 32 + l16) * 64 + c);
    }
    for (int s = 0; s < 2; s++)
      for (int mi = 0; mi < 4; mi++)
        for (int ni = 0; ni < 4; ni++)
          acc[mi][ni] = __builtin_amdgcn_mfma_f32_16x16x32_bf16(af[s][mi], bfr[s][ni], acc[mi][ni], 0, 0, 0);
    __syncthreads();
  }
  // ---- epilogue ----
  if (h >= 40) {  // V head: write Vt[vh][d][t] bf16 transposed
    int vh = h - 40;
    for (int mi = 0; mi < 4; mi++) {
      int t0 = row0 + wy * 64 + mi * 16 + quad * 4;
      for (int ni = 0; ni < 4; ni++) {
        int d = wx * 16 + ni * 32 + l16;
        u16x4 o;
        for (int r = 0; r < 4; r++) o[r] = f2bf(acc[mi][ni][r]);
        *(u16x4*)&Vt[(size_t)vh * (HD * NTOK) + (size_t)d * NTOK + t0] = o;
      }
    }
    return;
  }
  // Q/K head: RMSNorm + RoPE
  f32x4 ssv[4];
  for (int mi = 0; mi < 4; mi++)
    for (int r = 0; r < 4; r++) {
      float s = 0.f;
      for (int ni = 0; ni < 4; ni++) s += acc[mi][ni][r] * acc[mi][ni][r];
      ssv[mi][r] = s;
    }
  for (int m = 1; m < 16; m <<= 1)
    for (int mi = 0; mi < 4; mi++)
      for (int r = 0; r < 4; r++)
        ssv[mi][r] += __shfl_xor(ssv[mi][r], m);
  S[wx][wy][quad][l16] = ssv[l16 >> 2][l16 & 3];
  __syncthreads();
  f32x4 invv[4];
  for (int mi = 0; mi < 4; mi++) {
    f32x4 oss = *(const f32x4*)&S[1 - wx][wy][quad][mi * 4];
    for (int r = 0; r < 4; r++)
      invv[mi][r] = rsqrtf((ssv[mi][r] + oss[r]) * (1.0f / 128.0f) + 1e-6f);
  }
  const bool isQ = (h < 32);
  const float* w = isQ ? qw : kw;
  const float osc = isQ ? 0.08838834764831845f : 1.0f;  // fold 1/sqrt(128) into Q
  float w1[2], w2[2], fr[2];
  for (int ni = 0; ni < 2; ni++) {
    int d = wx * 16 + ni * 32 + l16;
    w1[ni] = w[d];
    w2[ni] = w[d + 64];
    fr[ni] = exp2f(-0.3114307588956805f * (float)d);  // 1e6^(-d/64)
  }
  u16* dstb; int ld;
  if (isQ) { dstb = Qn + h * 128; ld = NQ * HD; }
  else     { dstb = Kn + (h - 32) * 128; ld = NKV * HD; }
  for (int mi = 0; mi < 4; mi++)
    for (int r = 0; r < 4; r++) {
      int t = row0 + wy * 64 + mi * 16 + quad * 4 + r;
      float p = (float)pos[t];
      float s_ = invv[mi][r] * osc;
      u16* rowp = dstb + (size_t)t * ld;
      for (int ni = 0; ni < 2; ni++) {
        int d = wx * 16 + ni * 32 + l16;
        float a1 = acc[mi][ni][r] * w1[ni];
        float a2 = acc[mi][ni + 2][r] * w2[ni];
        float ang = p * fr[ni];
        float sn = sinf(ang), cs = cosf(ang);
        rowp[d]      = f2bf((a1 * cs - a2 * sn) * s_);
        rowp[d + 64] = f2bf((a2 * cs + a1 * sn) * s_);
      }
    }
}

// ---------------- GEMM: C[M][N] = A[M][K] * B[N][K]^T (out-proj, fp32 out) ----------------
__global__ __launch_bounds__(256, 3) void gemm_bt(const u16* __restrict__ A,
                                                  const u16* __restrict__ B,
                                                  float* __restrict__ C,
                                                  int M, int N, int K) {
  __shared__ u16 sA[128 * 64];
  __shared__ u16 sB[128 * 64];
  const int tid = threadIdx.x;
  const int wave = tid >> 6, lane = tid & 63;
  const int quad = lane >> 4, l16 = lane & 15;
  const int wy = wave >> 1, wx = wave & 1;
  const int row0 = blockIdx.y * 128, col0 = blockIdx.x * 128;
  f32x4 acc[4][4] = {};
  const int lr = lane >> 3;
  const int sc = (lane & 7) ^ lr;
  const u16* gA = A + (size_t)(row0 + wave * 32 + lr) * K + sc * 8;
  const u16* gB = B + (size_t)(col0 + wave * 32 + lr) * K + sc * 8;
  u16* lA = sA + wave * 32 * 64;
  u16* lB = sB + wave * 32 * 64;
  const int swz = l16 & 7;
  for (int k0 = 0; k0 < K; k0 += 64) {
    for (int j = 0; j < 4; j++) {
      __builtin_amdgcn_global_load_lds(
          (AS1 void*)(void*)(gA + k0 + (size_t)(j * 8) * K),
          (AS3 void*)(void*)(lA + j * 8 * 64), 16, 0, 0);
      __builtin_amdgcn_global_load_lds(
          (AS1 void*)(void*)(gB + k0 + (size_t)(j * 8) * K),
          (AS3 void*)(void*)(lB + j * 8 * 64), 16, 0, 0);
    }
    __syncthreads();
    bf16x8 af[2][4], bfr[2][4];
    for (int s = 0; s < 2; s++) {
      const int c = ((s * 4 + quad) ^ swz) * 8;
      for (int mi = 0; mi < 4; mi++) {
        af[s][mi] = *(const bf16x8*)(const void*)(sA + (wy * 64 + mi * 16 + l16) * 64 + c);
        bfr[s][mi] = *(const bf16x8*)(const void*)(sB + (wx * 64 + mi * 16 + l16) * 64 + c);
      }
    }
    for (int s = 0; s < 2; s++)
      for (int mi = 0; mi < 4; mi++)
        for (int ni = 0; ni < 4; ni++)
          acc[mi][ni] = __builtin_amdgcn_mfma_f32_16x16x32_bf16(af[s][mi], bfr[s][ni], acc[mi][ni], 0, 0, 0);
    __syncthreads();
  }
  for (int mi = 0; mi < 4; mi++)
    for (int ni = 0; ni < 4; ni++) {
      int row = row0 + wy * 64 + mi * 16 + quad * 4;
      int col = col0 + wx * 64 + ni * 16 + l16;
      float* cp = C + (size_t)row * N + col;
      for (int r = 0; r < 4; r++) cp[(size_t)r * N] = acc[mi][ni][r];
    }
}

// ---------------- flash attention: LDS-staged K/V, paired q-tiles, shift-softmax ----------------
__global__ __launch_bounds__(512) void flash2(const u16* __restrict__ Q,
                                              const u16* __restrict__ K,
                                              const u16* __restrict__ V,
                                              u16* __restrict__ O) {
  __shared__ u16 sK[64 * 136];
  __shared__ u16 sV[128 * 72];
  __shared__ u16 sP[8][16 * 72];
  const int p = blockIdx.x, h = blockIdx.y, kvh = h >> 2;
  const int tid = threadIdx.x;
  const int wave = tid >> 6, lane = tid & 63;
  const int quad = lane >> 4, l16 = lane & 15;
  u16* myP = &sP[wave][0];
  const u16* Vh = V + (size_t)kvh * (HD * NTOK);
  const int qtiles[2] = {p, 15 - p};
  const int rk0 = tid >> 4, ck0 = tid & 15;
  const int rv0 = tid >> 3, cv0 = tid & 7;
  for (int ti = 0; ti < 2; ti++) {
    const int qb = qtiles[ti];
    const int qrow0 = qb * 128 + wave * 16;
    bf16x8 qf[4];
    for (int ks = 0; ks < 4; ks++)
      qf[ks] = *(const bf16x8*)(const void*)(Q + (size_t)(qrow0 + l16) * (NQ * HD) + h * HD + ks * 32 + quad * 8);
    f32x4 accO[8] = {};
    float l_r[4] = {0.f, 0.f, 0.f, 0.f};
    const int nU = 2 * (qb + 1);
    const int myMax = (qrow0 + 15) >> 6;
    for (int kb = 0; kb < nU; kb++) {
      u16x8 k0 = *(const u16x8*)(const void*)(K + (size_t)(kb * 64 + rk0) * (NKV * HD) + kvh * HD + ck0 * 8);
      u16x8 k1 = *(const u16x8*)(const void*)(K + (size_t)(kb * 64 + rk0 + 32) * (NKV * HD) + kvh * HD + ck0 * 8);
      u16x8 v0 = *(const u16x8*)(const void*)(Vh + (size_t)rv0 * NTOK + kb * 64 + cv0 * 8);
      u16x8 v1 = *(const u16x8*)(const void*)(Vh + (size_t)(rv0 + 64) * NTOK + kb * 64 + cv0 * 8);
      __syncthreads();
      *(u16x8*)(void*)(sK + rk0 * 136 + ck0 * 8) = k0;
      *(u16x8*)(void*)(sK + (rk0 + 32) * 136 + ck0 * 8) = k1;
      *(u16x8*)(void*)(sV + rv0 * 72 + cv0 * 8) = v0;
      *(u16x8*)(void*)(sV + (rv0 + 64) * 72 + cv0 * 8) = v1;
      __syncthreads();
      if (kb <= myMax) {
        f32x4 s[4] = {};
        for (int ks = 0; ks < 4; ks++)
          for (int nt = 0; nt < 4; nt++) {
            bf16x8 kf = *(const bf16x8*)(const void*)(sK + (nt * 16 + l16) * 136 + ks * 32 + quad * 8);
            s[nt] = __builtin_amdgcn_mfma_f32_16x16x32_bf16(qf[ks], kf, s[nt], 0, 0, 0);
          }
        const int qg = qrow0 + quad * 4;
        for (int nt = 0; nt < 4; nt++) {
          int tok = kb * 64 + nt * 16 + l16;
          for (int r = 0; r < 4; r++) {
            float e = __expf(s[nt][r]);
            float pv = (tok <= qg + r) ? e : 0.0f;
            l_r[r] += pv;
            myP[(quad * 4 + r) * 72 + nt * 16 + l16] = f2bf(pv);
          }
        }
        asm volatile("s_waitcnt lgkmcnt(0)" ::: "memory");
        for (int ks = 0; ks < 2; ks++) {
          bf16x8 pf = *(const bf16x8*)(const void*)(myP + l16 * 72 + ks * 32 + quad * 8);
          for (int nt = 0; nt < 8; nt++) {
            bf16x8 vf = *(const bf16x8*)(const void*)(sV + (nt * 16 + l16) * 72 + ks * 32 + quad * 8);
            accO[nt] = __builtin_amdgcn_mfma_f32_16x16x32_bf16(pf, vf, accO[nt], 0, 0, 0);
          }
        }
      }
    }
    float inv[4];
    for (int r = 0; r < 4; r++) {
      float t = l_r[r];
      t += __shfl_xor(t, 1);
      t += __shfl_xor(t, 2);
      t += __shfl_xor(t, 4);
      t += __shfl_xor(t, 8);
      inv[r] = 1.0f / t;
    }
    for (int nt = 0; nt < 8; nt++)
      for (int r = 0; r < 4; r++)
        O[(size_t)(qrow0 + quad * 4 + r) * (NQ * HD) + h * HD + nt * 16 + l16] =
            f2bf(accO[nt][r] * inv[r]);
  }
}

extern "C" void kernel_launch(void* const* d_in, const int* in_sizes, int n_in,
                              void* d_out, int out_size, void* d_ws, size_t ws_size,
                              hipStream_t stream) {
  const float* hidden = (const float*)d_in[0];
  const int* positions = (const int*)d_in[1];
  const float* Wq = (const float*)d_in[2];
  const float* Wk = (const float*)d_in[3];
  const float* Wv = (const float*)d_in[4];
  const float* Wo = (const float*)d_in[5];
  const float* qw = (const float*)d_in[6];
  const float* kw = (const float*)d_in[7];
  char* ws = (char*)d_ws;
  u16* hid_bf  = (u16*)(ws);                      // 16 MB
  u16* WqkvT   = (u16*)(ws + (size_t)16*1048576); // 48 MB
  u16* WoT     = (u16*)(ws + (size_t)64*1048576); // 32 MB
  u16* Qn      = (u16*)(ws + (size_t)96*1048576); // 16 MB
  u16* Kn      = (u16*)(ws + (size_t)112*1048576);//  4 MB
  u16* Vt      = (u16*)(ws + (size_t)116*1048576);//  4 MB
  u16* AO      = (u16*)(ws + (size_t)120*1048576);// 16 MB
  float* outp  = (float*)d_out;

  prep<<<18432, 256, 0, stream>>>(hidden, hid_bf, Wq, Wk, Wv, Wo, WqkvT, WoT);
  gemm_qkv<<<dim3(48, 16), 256, 0, stream>>>(hid_bf, WqkvT, positions, qw, kw, Qn, Kn, Vt);
  flash2<<<dim3(8, 32), 512, 0, stream>>>(Qn, Kn, Vt, AO);
  gemm_bt<<<dim3(32, 16), 256, 0, stream>>>(AO, WoT, outp, 2048, 4096, 4096);
}